// Round 16
// baseline (266.521 us; speedup 1.0000x reference)
//
#include <hip/hip_runtime.h>

#define TOKENS 16384
#define DDIM 4096
#define RANK 32
#define TOPK 8
#define KCH 8                        // K-chunks -> y_part planes
#define KSTEPS ((DDIM / KCH) / 32)   // 16 MFMA K-steps per chunk
#define TAU 2e-3f                    // routing-gap margin: flag if below

typedef __attribute__((ext_vector_type(8))) short bf16x8;  // 8 bf16 (4 VGPR)
typedef __attribute__((ext_vector_type(4))) float f32x4;

// ---------------- K0: split A into hi/lo bf16; zero the flag counter ------
__global__ __launch_bounds__(256) void k0_splitA(const float* __restrict__ A,
                                                 ushort* __restrict__ Ah,
                                                 ushort* __restrict__ Al,
                                                 int* __restrict__ flag_cnt) {
  const int i = blockIdx.x * 256 + threadIdx.x;  // 0 .. RANK*DDIM-1
  if (i == 0) *flag_cnt = 0;
  const float a = A[i];
  const unsigned ab = __float_as_uint(a);
  const float hf = __uint_as_float(ab & 0xFFFF0000u);
  const float r = a - hf;
  Ah[i] = (ushort)(ab >> 16);
  Al[i] = (ushort)(__float_as_uint(r) >> 16);
}

// ---------------- K1: y_part[kc][t][r] via mfma_f32_16x16x32_bf16 ----------
// y ~= xh*Ah + xh*Al + xl*Ah (delta ~1e-5); routing certified in k2 / fixed
// in k2b. Byte-identical to r13 (best total so far).
__global__ __launch_bounds__(256) void k1_mfma(const float* __restrict__ x,
                                               const ushort* __restrict__ Ah,
                                               const ushort* __restrict__ Al,
                                               float* __restrict__ y_part) {
  const int tid = threadIdx.x;
  const int lane = tid & 63;
  const int wv = tid >> 6;
  const int t0 = blockIdx.x * 64 + wv * 16;
  const int kc = blockIdx.y;
  const int k0 = kc * (DDIM / KCH);

  const int mrow = lane & 15;  // token (A-op) / rank (B-op)
  const int kg = lane >> 4;    // k-group of 8 dims

  f32x4 acc0 = {0.f, 0.f, 0.f, 0.f};  // ranks 0..15
  f32x4 acc1 = {0.f, 0.f, 0.f, 0.f};  // ranks 16..31

  const float* xp = &x[(size_t)(t0 + mrow) * DDIM + k0 + kg * 8];
  const ushort* ah0 = &Ah[(size_t)mrow * DDIM + k0 + kg * 8];
  const ushort* ah1 = &Ah[(size_t)(mrow + 16) * DDIM + k0 + kg * 8];
  const ushort* al0 = &Al[(size_t)mrow * DDIM + k0 + kg * 8];
  const ushort* al1 = &Al[(size_t)(mrow + 16) * DDIM + k0 + kg * 8];

#pragma unroll 2
  for (int ks = 0; ks < KSTEPS; ++ks) {
    const float4 xa = *reinterpret_cast<const float4*>(xp + ks * 32);
    const float4 xb = *reinterpret_cast<const float4*>(xp + ks * 32 + 4);
    const bf16x8 bh0 = *reinterpret_cast<const bf16x8*>(ah0 + ks * 32);
    const bf16x8 bh1 = *reinterpret_cast<const bf16x8*>(ah1 + ks * 32);
    const bf16x8 bl0 = *reinterpret_cast<const bf16x8*>(al0 + ks * 32);
    const bf16x8 bl1 = *reinterpret_cast<const bf16x8*>(al1 + ks * 32);

    const float xf[8] = {xa.x, xa.y, xa.z, xa.w, xb.x, xb.y, xb.z, xb.w};
    bf16x8 xh, xl;
#pragma unroll
    for (int j = 0; j < 8; ++j) {  // constant indices only (no scratch)
      const unsigned b = __float_as_uint(xf[j]);
      xh[j] = (short)(b >> 16);
      const float r = xf[j] - __uint_as_float(b & 0xFFFF0000u);
      xl[j] = (short)(__float_as_uint(r) >> 16);
    }

    acc0 = __builtin_amdgcn_mfma_f32_16x16x32_bf16(xh, bh0, acc0, 0, 0, 0);
    acc1 = __builtin_amdgcn_mfma_f32_16x16x32_bf16(xh, bh1, acc1, 0, 0, 0);
    acc0 = __builtin_amdgcn_mfma_f32_16x16x32_bf16(xh, bl0, acc0, 0, 0, 0);
    acc1 = __builtin_amdgcn_mfma_f32_16x16x32_bf16(xh, bl1, acc1, 0, 0, 0);
    acc0 = __builtin_amdgcn_mfma_f32_16x16x32_bf16(xl, bh0, acc0, 0, 0, 0);
    acc1 = __builtin_amdgcn_mfma_f32_16x16x32_bf16(xl, bh1, acc1, 0, 0, 0);
  }

  // D: token = t0 + kg*4 + i, rank = mrow (acc0) / mrow+16 (acc1)
  float* yp = &y_part[((size_t)kc * TOKENS + t0 + kg * 4) * RANK + mrow];
#pragma unroll
  for (int i = 0; i < 4; ++i) {
    yp[(size_t)i * RANK] = acc0[i];
    yp[(size_t)i * RANK + 16] = acc1[i];
  }
}

// ---------------- K2: reduce, top-8 + gap margin; flag ambiguous ----------
__global__ __launch_bounds__(64) void k2_topk(const float* __restrict__ y_part,
                                              const float* __restrict__ dbias,
                                              float* __restrict__ w,
                                              int* __restrict__ flag_cnt,
                                              int* __restrict__ flag_list) {
  const int t = blockIdx.x * 64 + threadIdx.x;
  float yv[RANK];
#pragma unroll
  for (int r = 0; r < RANK; ++r) yv[r] = 0.f;
#pragma unroll
  for (int c = 0; c < KCH; ++c) {
    const float* yp = &y_part[((size_t)c * TOKENS + t) * RANK];
#pragma unroll
    for (int q = 0; q < RANK / 4; ++q) {
      const float4 v = reinterpret_cast<const float4*>(yp)[q];
      yv[q * 4 + 0] += v.x; yv[q * 4 + 1] += v.y;
      yv[q * 4 + 2] += v.z; yv[q * 4 + 3] += v.w;
    }
  }

  float ab[RANK];
#pragma unroll
  for (int r = 0; r < RANK; ++r) ab[r] = fabsf(yv[r] + dbias[r]);

  unsigned mask = 0;
  float best8 = 0.f;
#pragma unroll
  for (int k = 0; k < TOPK; ++k) {
    float best = -1.f;
    int bi = 0;
#pragma unroll
    for (int r = 0; r < RANK; ++r) {
      // strict > keeps lowest index on ties == jax.lax.top_k stability
      const bool sel = (((mask >> r) & 1u) == 0u) && (ab[r] > best);
      best = sel ? ab[r] : best;
      bi = sel ? r : bi;
    }
    mask |= 1u << bi;
    best8 = best;
  }
  float ninth = -1.f;
#pragma unroll
  for (int r = 0; r < RANK; ++r) {
    const bool un = ((mask >> r) & 1u) == 0u;
    ninth = (un && ab[r] > ninth) ? ab[r] : ninth;
  }
  if (best8 - ninth < TAU) {  // split-y can't certify fp32 decision
    const int idx = atomicAdd(flag_cnt, 1);
    flag_list[idx] = t;
  }

  float* wp = &w[(size_t)t * RANK];
#pragma unroll
  for (int q = 0; q < RANK / 4; ++q) {
    float4 o;
    o.x = ((mask >> (q * 4 + 0)) & 1u) ? 2.0f * yv[q * 4 + 0] : 0.f;
    o.y = ((mask >> (q * 4 + 1)) & 1u) ? 2.0f * yv[q * 4 + 1] : 0.f;
    o.z = ((mask >> (q * 4 + 2)) & 1u) ? 2.0f * yv[q * 4 + 2] : 0.f;
    o.w = ((mask >> (q * 4 + 3)) & 1u) ? 2.0f * yv[q * 4 + 3] : 0.f;
    reinterpret_cast<float4*>(wp)[q] = o;
  }
}

// ---------------- K2b: exact fp32 re-route for flagged tokens -------------
__global__ __launch_bounds__(256) void k2b_refine(
    const float* __restrict__ x, const float* __restrict__ A,
    const float* __restrict__ dbias, const int* __restrict__ flag_cnt,
    const int* __restrict__ flag_list, float* __restrict__ w) {
  __shared__ float part[8][RANK];
  __shared__ float yv_s[RANK];
  __shared__ unsigned mask_s;
  const int cnt = *flag_cnt;
  const int rank = threadIdx.x & 31;
  const int seg = threadIdx.x >> 5;

  for (int i = blockIdx.x; i < cnt; i += gridDim.x) {
    const int t = flag_list[i];
    const float4* xr =
        reinterpret_cast<const float4*>(&x[(size_t)t * DDIM + seg * 512]);
    const float4* Ar =
        reinterpret_cast<const float4*>(&A[(size_t)rank * DDIM + seg * 512]);
    float s = 0.f;
    for (int c = 0; c < 128; c += 4) {  // 16-dim sub-sums, two-level fp32
      float ss = 0.f;
#pragma unroll
      for (int u = 0; u < 4; ++u) {
        const float4 xv = xr[c + u];
        const float4 av = Ar[c + u];
        ss = fmaf(xv.x, av.x, ss);
        ss = fmaf(xv.y, av.y, ss);
        ss = fmaf(xv.z, av.z, ss);
        ss = fmaf(xv.w, av.w, ss);
      }
      s += ss;
    }
    part[seg][rank] = s;
    __syncthreads();
    if (threadIdx.x < 32) {
      float y = 0.f;
#pragma unroll
      for (int g = 0; g < 8; ++g) y += part[g][threadIdx.x];
      yv_s[threadIdx.x] = y;
    }
    __syncthreads();
    if (threadIdx.x == 0) {
      float ab[RANK];
#pragma unroll
      for (int r = 0; r < RANK; ++r) ab[r] = fabsf(yv_s[r] + dbias[r]);
      unsigned mask = 0;
#pragma unroll
      for (int k = 0; k < TOPK; ++k) {
        float best = -1.f;
        int bi = 0;
#pragma unroll
        for (int r = 0; r < RANK; ++r) {
          const bool sel = (((mask >> r) & 1u) == 0u) && (ab[r] > best);
          best = sel ? ab[r] : best;
          bi = sel ? r : bi;
        }
        mask |= 1u << bi;
      }
      mask_s = mask;
    }
    __syncthreads();
    if (threadIdx.x < 32) {
      w[(size_t)t * RANK + rank] =
          ((mask_s >> rank) & 1u) ? 2.0f * yv_s[rank] : 0.f;
    }
    __syncthreads();  // protect LDS reuse next iteration
  }
}

// ---------------- K3: out[t][o] = sum_r w[t][r] * B[o][r] ----------------
// grid (DDIM/512, TOKENS/64), block 256, NO LDS. w row addresses are
// block-uniform (blockIdx.y + loop const) + __restrict__ -> s_load_dwordx16
// on the SCALAR pipe. This removes the DS-pipe serialization that cost ~82us
// (4 waves x 64 tokens x 8 ds_read_b128 x 12cy x 8 blk/CU = 196K cy/CU):
// SALU issue runs parallel to VALU, and 32 FMAs/token cover the K$ hit.
#define K3_TOK 64

__global__ __launch_bounds__(256) void k3_out(const float* __restrict__ w,
                                              const float* __restrict__ B,
                                              float* __restrict__ out) {
  const int tid = threadIdx.x;
  const int c0 = blockIdx.x * 512 + tid * 2;
  const int tbase = blockIdx.y * K3_TOK;

  float b0[RANK], b1[RANK];
#pragma unroll
  for (int q = 0; q < RANK / 4; ++q) {
    const float4 v0 = reinterpret_cast<const float4*>(&B[(size_t)c0 * RANK])[q];
    const float4 v1 =
        reinterpret_cast<const float4*>(&B[(size_t)(c0 + 1) * RANK])[q];
    b0[q * 4 + 0] = v0.x; b0[q * 4 + 1] = v0.y;
    b0[q * 4 + 2] = v0.z; b0[q * 4 + 3] = v0.w;
    b1[q * 4 + 0] = v1.x; b1[q * 4 + 1] = v1.y;
    b1[q * 4 + 2] = v1.z; b1[q * 4 + 3] = v1.w;
  }

#pragma unroll 2
  for (int tt = 0; tt < K3_TOK; ++tt) {
    // uniform address -> scalar loads (SGPRs); unroll 2 keeps live w-window
    // at 64 SGPRs so the compiler can prefetch one token ahead.
    const float* wp = &w[(size_t)(tbase + tt) * RANK];
    float s0 = 0.f, s1 = 0.f;
#pragma unroll
    for (int r = 0; r < RANK; ++r) {
      const float wv = wp[r];
      s0 = fmaf(wv, b0[r], s0);
      s1 = fmaf(wv, b1[r], s1);
    }
    float2 o;
    o.x = s0;
    o.y = s1;
    *reinterpret_cast<float2*>(&out[(size_t)(tbase + tt) * DDIM + c0]) = o;
  }
}

extern "C" void kernel_launch(void* const* d_in, const int* in_sizes, int n_in,
                              void* d_out, int out_size, void* d_ws,
                              size_t ws_size, hipStream_t stream) {
  const float* x = (const float*)d_in[0];
  const float* A = (const float*)d_in[1];
  const float* B = (const float*)d_in[2];
  const float* dbias = (const float*)d_in[3];
  float* out = (float*)d_out;

  const size_t plane = (size_t)TOKENS * RANK;   // 512K floats = 2 MB
  float* y_part = (float*)d_ws;                 // KCH planes (16 MB)
  float* w = y_part + (size_t)KCH * plane;      // 1 plane (2 MB)
  ushort* Ah = (ushort*)(w + plane);            // 256 KB
  ushort* Al = Ah + (size_t)RANK * DDIM;        // 256 KB
  int* flag_cnt = (int*)(Al + (size_t)RANK * DDIM);
  int* flag_list = flag_cnt + 4;                // capacity TOKENS (64 KB)

  k0_splitA<<<(RANK * DDIM) / 256, 256, 0, stream>>>(A, Ah, Al, flag_cnt);
  k1_mfma<<<dim3(TOKENS / 64, KCH), 256, 0, stream>>>(x, Ah, Al, y_part);
  k2_topk<<<TOKENS / 64, 64, 0, stream>>>(y_part, dbias, w, flag_cnt,
                                          flag_list);
  k2b_refine<<<512, 256, 0, stream>>>(x, A, dbias, flag_cnt, flag_list, w);
  k3_out<<<dim3(DDIM / 512, TOKENS / K3_TOK), 256, 0, stream>>>(w, B, out);
}

// Round 17
// 234.017 us; speedup vs baseline: 1.1389x; 1.1389x over previous
//
#include <hip/hip_runtime.h>

#define TOKENS 16384
#define DDIM 4096
#define RANK 32
#define TOPK 8
#define KCH 8        // K-chunks -> y_part planes (512 dims each)
#define TAU 2e-3f    // routing-gap margin: flag if below
#define ROWF 260     // LDS floats per x row: 256 + 4 pad

typedef __attribute__((ext_vector_type(8))) short bf16x8;  // 8 bf16 (4 VGPR)
typedef __attribute__((ext_vector_type(4))) float f32x4;

// global -> LDS async DMA, 16B per lane (wave-uniform LDS base + lane*16)
__device__ __forceinline__ void dma16(const float* g, float* l) {
  __builtin_amdgcn_global_load_lds(
      (const __attribute__((address_space(1))) unsigned int*)g,
      (__attribute__((address_space(3))) unsigned int*)l, 16, 0, 0);
}

// ---------------- K0: pack A into MFMA-fragment order, hi/lo bf16 ---------
// Apk[((kc*16+ks)*4+s)*64 + lane] = 8 bf16 that lane (mrow=lane&15,
// kg=lane>>4) consumes at (kc,ks) for stream s (0:h row, 1:h row+16,
// 2:l row, 3:l row+16). Every k1 A-load becomes ONE coalesced 1KB
// instruction — kills the 16-line gathers that were k1's wall (r13/r15:
// 64 gather-instrs/wave x ~16-60cy TA/L1 occupancy each ~= 100+ us/CU).
__global__ __launch_bounds__(256) void k0_packA(const float* __restrict__ A,
                                                bf16x8* __restrict__ Apk,
                                                int* __restrict__ flag_cnt) {
  const int i = blockIdx.x * 256 + threadIdx.x;  // 0 .. 32767
  if (i == 0) *flag_cnt = 0;
  const int lane = i & 63;
  const int s = (i >> 6) & 3;
  const int ks = (i >> 8) & 15;
  const int kc = i >> 12;
  const int mrow = lane & 15;
  const int kg = lane >> 4;
  const int row = (s & 1) ? mrow + 16 : mrow;
  const int col = kc * 512 + ks * 32 + kg * 8;
  const float* src = &A[(size_t)row * DDIM + col];
  bf16x8 o;
#pragma unroll
  for (int j = 0; j < 8; ++j) {
    const float a = src[j];
    const unsigned b = __float_as_uint(a);
    if (s < 2) {
      o[j] = (short)(b >> 16);  // hi = truncate-to-bf16
    } else {
      const float hf = __uint_as_float(b & 0xFFFF0000u);
      const float r = a - hf;   // lo = residual as bf16
      o[j] = (short)(__float_as_uint(r) >> 16);
    }
  }
  Apk[i] = o;
}

// ---------------- K1: y_part[kc][t][r] via mfma_f32_16x16x32_bf16 ----------
// y ~= xh*Ah + xh*Al + xl*Ah; routing certified in k2 / fixed in k2b.
// x staged via global_load_lds DMA (coalesced, VGPR-free, wave-private; r15
// structure, which passed). A from Apk: 4 coalesced loads per K-step,
// L2-resident. ZERO divergent-address load instructions remain.
__global__ __launch_bounds__(256) void k1_mfma(const float* __restrict__ x,
                                               const bf16x8* __restrict__ Apk,
                                               float* __restrict__ y_part) {
  const int tid = threadIdx.x;
  const int lane = tid & 63;
  const int wv = __builtin_amdgcn_readfirstlane(tid >> 6);
  const int t0 = blockIdx.x * 64 + wv * 16;
  const int kc = blockIdx.y;

  __shared__ float xs[4 * 16 * ROWF];  // 66,560 B -> 2 blocks/CU
  float* xw = &xs[wv * 16 * ROWF];

  const int mrow = lane & 15;  // token (A-op) / rank (B-op)
  const int kg = lane >> 4;    // k-group of 8 dims

  f32x4 acc0 = {0.f, 0.f, 0.f, 0.f};  // ranks 0..15
  f32x4 acc1 = {0.f, 0.f, 0.f, 0.f};  // ranks 16..31

  const bf16x8* ap = Apk + ((size_t)kc << 12) + lane;  // 4096 frags per kc

  // ---- DMA sub0: 16 rows x 1KB, all 16 outstanding ----
#pragma unroll
  for (int r = 0; r < 16; ++r)
    dma16(&x[(size_t)(t0 + r) * DDIM + kc * 512 + lane * 4], xw + r * ROWF);

#pragma unroll
  for (int sub = 0; sub < 2; ++sub) {
    asm volatile("s_waitcnt vmcnt(0)" ::: "memory");  // this wave's DMAs done
    __builtin_amdgcn_sched_barrier(0);

#pragma unroll
    for (int ks8 = 0; ks8 < 8; ++ks8) {
      const int ks = sub * 8 + ks8;
      const float* xrow = xw + mrow * ROWF + ks8 * 32 + kg * 8;
      const float4 f0 = *reinterpret_cast<const float4*>(xrow);
      const float4 f1 = *reinterpret_cast<const float4*>(xrow + 4);

      const bf16x8 bh0 = ap[(ks * 4 + 0) * 64];
      const bf16x8 bh1 = ap[(ks * 4 + 1) * 64];
      const bf16x8 bl0 = ap[(ks * 4 + 2) * 64];
      const bf16x8 bl1 = ap[(ks * 4 + 3) * 64];

      const float xf[8] = {f0.x, f0.y, f0.z, f0.w, f1.x, f1.y, f1.z, f1.w};
      bf16x8 xh, xl;
#pragma unroll
      for (int j = 0; j < 8; ++j) {  // constant indices only (no scratch)
        const unsigned b = __float_as_uint(xf[j]);
        xh[j] = (short)(b >> 16);
        const float rr = xf[j] - __uint_as_float(b & 0xFFFF0000u);
        xl[j] = (short)(__float_as_uint(rr) >> 16);
      }

      acc0 = __builtin_amdgcn_mfma_f32_16x16x32_bf16(xh, bh0, acc0, 0, 0, 0);
      acc1 = __builtin_amdgcn_mfma_f32_16x16x32_bf16(xh, bh1, acc1, 0, 0, 0);
      acc0 = __builtin_amdgcn_mfma_f32_16x16x32_bf16(xh, bl0, acc0, 0, 0, 0);
      acc1 = __builtin_amdgcn_mfma_f32_16x16x32_bf16(xh, bl1, acc1, 0, 0, 0);
      acc0 = __builtin_amdgcn_mfma_f32_16x16x32_bf16(xl, bh0, acc0, 0, 0, 0);
      acc1 = __builtin_amdgcn_mfma_f32_16x16x32_bf16(xl, bh1, acc1, 0, 0, 0);
    }

    if (sub == 0) {
      // all ds_reads of sub0 delivered before overwriting the buffer
      asm volatile("s_waitcnt lgkmcnt(0)" ::: "memory");
      __builtin_amdgcn_sched_barrier(0);
#pragma unroll
      for (int r = 0; r < 16; ++r)
        dma16(&x[(size_t)(t0 + r) * DDIM + kc * 512 + 256 + lane * 4],
              xw + r * ROWF);
    }
  }

  // D: token = t0 + kg*4 + i, rank = mrow (acc0) / mrow+16 (acc1)
  float* yp = &y_part[((size_t)kc * TOKENS + t0 + kg * 4) * RANK + mrow];
#pragma unroll
  for (int i = 0; i < 4; ++i) {
    yp[(size_t)i * RANK] = acc0[i];
    yp[(size_t)i * RANK + 16] = acc1[i];
  }
}

// ---------------- K2: reduce, top-8 + gap margin; flag ambiguous ----------
__global__ __launch_bounds__(64) void k2_topk(const float* __restrict__ y_part,
                                              const float* __restrict__ dbias,
                                              float* __restrict__ w,
                                              int* __restrict__ flag_cnt,
                                              int* __restrict__ flag_list) {
  const int t = blockIdx.x * 64 + threadIdx.x;
  float yv[RANK];
#pragma unroll
  for (int r = 0; r < RANK; ++r) yv[r] = 0.f;
#pragma unroll
  for (int c = 0; c < KCH; ++c) {
    const float* yp = &y_part[((size_t)c * TOKENS + t) * RANK];
#pragma unroll
    for (int q = 0; q < RANK / 4; ++q) {
      const float4 v = reinterpret_cast<const float4*>(yp)[q];
      yv[q * 4 + 0] += v.x; yv[q * 4 + 1] += v.y;
      yv[q * 4 + 2] += v.z; yv[q * 4 + 3] += v.w;
    }
  }

  float ab[RANK];
#pragma unroll
  for (int r = 0; r < RANK; ++r) ab[r] = fabsf(yv[r] + dbias[r]);

  unsigned mask = 0;
  float best8 = 0.f;
#pragma unroll
  for (int k = 0; k < TOPK; ++k) {
    float best = -1.f;
    int bi = 0;
#pragma unroll
    for (int r = 0; r < RANK; ++r) {
      // strict > keeps lowest index on ties == jax.lax.top_k stability
      const bool sel = (((mask >> r) & 1u) == 0u) && (ab[r] > best);
      best = sel ? ab[r] : best;
      bi = sel ? r : bi;
    }
    mask |= 1u << bi;
    best8 = best;
  }
  float ninth = -1.f;
#pragma unroll
  for (int r = 0; r < RANK; ++r) {
    const bool un = ((mask >> r) & 1u) == 0u;
    ninth = (un && ab[r] > ninth) ? ab[r] : ninth;
  }
  if (best8 - ninth < TAU) {  // split-y can't certify fp32 decision
    const int idx = atomicAdd(flag_cnt, 1);
    flag_list[idx] = t;
  }

  float* wp = &w[(size_t)t * RANK];
#pragma unroll
  for (int q = 0; q < RANK / 4; ++q) {
    float4 o;
    o.x = ((mask >> (q * 4 + 0)) & 1u) ? 2.0f * yv[q * 4 + 0] : 0.f;
    o.y = ((mask >> (q * 4 + 1)) & 1u) ? 2.0f * yv[q * 4 + 1] : 0.f;
    o.z = ((mask >> (q * 4 + 2)) & 1u) ? 2.0f * yv[q * 4 + 2] : 0.f;
    o.w = ((mask >> (q * 4 + 3)) & 1u) ? 2.0f * yv[q * 4 + 3] : 0.f;
    reinterpret_cast<float4*>(wp)[q] = o;
  }
}

// ---------------- K2b: exact fp32 re-route for flagged tokens -------------
__global__ __launch_bounds__(256) void k2b_refine(
    const float* __restrict__ x, const float* __restrict__ A,
    const float* __restrict__ dbias, const int* __restrict__ flag_cnt,
    const int* __restrict__ flag_list, float* __restrict__ w) {
  __shared__ float part[8][RANK];
  __shared__ float yv_s[RANK];
  __shared__ unsigned mask_s;
  const int cnt = *flag_cnt;
  const int rank = threadIdx.x & 31;
  const int seg = threadIdx.x >> 5;

  for (int i = blockIdx.x; i < cnt; i += gridDim.x) {
    const int t = flag_list[i];
    const float4* xr =
        reinterpret_cast<const float4*>(&x[(size_t)t * DDIM + seg * 512]);
    const float4* Ar =
        reinterpret_cast<const float4*>(&A[(size_t)rank * DDIM + seg * 512]);
    float s = 0.f;
    for (int c = 0; c < 128; c += 4) {  // 16-dim sub-sums, two-level fp32
      float ss = 0.f;
#pragma unroll
      for (int u = 0; u < 4; ++u) {
        const float4 xv = xr[c + u];
        const float4 av = Ar[c + u];
        ss = fmaf(xv.x, av.x, ss);
        ss = fmaf(xv.y, av.y, ss);
        ss = fmaf(xv.z, av.z, ss);
        ss = fmaf(xv.w, av.w, ss);
      }
      s += ss;
    }
    part[seg][rank] = s;
    __syncthreads();
    if (threadIdx.x < 32) {
      float y = 0.f;
#pragma unroll
      for (int g = 0; g < 8; ++g) y += part[g][threadIdx.x];
      yv_s[threadIdx.x] = y;
    }
    __syncthreads();
    if (threadIdx.x == 0) {
      float ab[RANK];
#pragma unroll
      for (int r = 0; r < RANK; ++r) ab[r] = fabsf(yv_s[r] + dbias[r]);
      unsigned mask = 0;
#pragma unroll
      for (int k = 0; k < TOPK; ++k) {
        float best = -1.f;
        int bi = 0;
#pragma unroll
        for (int r = 0; r < RANK; ++r) {
          const bool sel = (((mask >> r) & 1u) == 0u) && (ab[r] > best);
          best = sel ? ab[r] : best;
          bi = sel ? r : bi;
        }
        mask |= 1u << bi;
      }
      mask_s = mask;
    }
    __syncthreads();
    if (threadIdx.x < 32) {
      w[(size_t)t * RANK + rank] =
          ((mask_s >> rank) & 1u) ? 2.0f * yv_s[rank] : 0.f;
    }
    __syncthreads();  // protect LDS reuse next iteration
  }
}

// ---------------- K3: out[t][o] = sum_r w[t][r] * B[o][r] ----------------
// r13 LDS version (r16's scalar s_load variant was -17us: lgkmcnt(0) drain
// serialization beats the DS-pipe cost).
#define K3_TOK 64

__global__ __launch_bounds__(256) void k3_out(const float* __restrict__ w,
                                              const float* __restrict__ B,
                                              float* __restrict__ out) {
  const int tid = threadIdx.x;
  const int c0 = blockIdx.x * 512 + tid * 2;
  const int tbase = blockIdx.y * K3_TOK;

  __shared__ float wl[K3_TOK * RANK];  // 8 KB

  float b0[RANK], b1[RANK];
#pragma unroll
  for (int q = 0; q < RANK / 4; ++q) {
    const float4 v0 = reinterpret_cast<const float4*>(&B[(size_t)c0 * RANK])[q];
    const float4 v1 =
        reinterpret_cast<const float4*>(&B[(size_t)(c0 + 1) * RANK])[q];
    b0[q * 4 + 0] = v0.x; b0[q * 4 + 1] = v0.y;
    b0[q * 4 + 2] = v0.z; b0[q * 4 + 3] = v0.w;
    b1[q * 4 + 0] = v1.x; b1[q * 4 + 1] = v1.y;
    b1[q * 4 + 2] = v1.z; b1[q * 4 + 3] = v1.w;
  }

  const float4* wg = reinterpret_cast<const float4*>(&w[(size_t)tbase * RANK]);
#pragma unroll
  for (int jj = 0; jj < 2; ++jj) {
    const int slot = tid + 256 * jj;  // 512 float4 slots
    reinterpret_cast<float4*>(wl)[slot] = wg[slot];
  }
  __syncthreads();

#pragma unroll 4
  for (int tt = 0; tt < K3_TOK; ++tt) {
    float s0 = 0.f, s1 = 0.f;
#pragma unroll
    for (int q = 0; q < RANK / 4; ++q) {
      const float4 wv = reinterpret_cast<const float4*>(wl)[tt * 8 + q];
      s0 = fmaf(wv.x, b0[q * 4 + 0], s0); s1 = fmaf(wv.x, b1[q * 4 + 0], s1);
      s0 = fmaf(wv.y, b0[q * 4 + 1], s0); s1 = fmaf(wv.y, b1[q * 4 + 1], s1);
      s0 = fmaf(wv.z, b0[q * 4 + 2], s0); s1 = fmaf(wv.z, b1[q * 4 + 2], s1);
      s0 = fmaf(wv.w, b0[q * 4 + 3], s0); s1 = fmaf(wv.w, b1[q * 4 + 3], s1);
    }
    float2 o;
    o.x = s0;
    o.y = s1;
    *reinterpret_cast<float2*>(&out[(size_t)(tbase + tt) * DDIM + c0]) = o;
  }
}

extern "C" void kernel_launch(void* const* d_in, const int* in_sizes, int n_in,
                              void* d_out, int out_size, void* d_ws,
                              size_t ws_size, hipStream_t stream) {
  const float* x = (const float*)d_in[0];
  const float* A = (const float*)d_in[1];
  const float* B = (const float*)d_in[2];
  const float* dbias = (const float*)d_in[3];
  float* out = (float*)d_out;

  const size_t plane = (size_t)TOKENS * RANK;   // 512K floats = 2 MB
  float* y_part = (float*)d_ws;                 // KCH planes (16 MB)
  float* w = y_part + (size_t)KCH * plane;      // 1 plane (2 MB)
  bf16x8* Apk = (bf16x8*)(w + plane);           // 32768 frags = 512 KB
  int* flag_cnt = (int*)(Apk + 32768);
  int* flag_list = flag_cnt + 4;                // capacity TOKENS (64 KB)

  k0_packA<<<128, 256, 0, stream>>>(A, Apk, flag_cnt);
  k1_mfma<<<dim3(TOKENS / 64, KCH), 256, 0, stream>>>(x, Apk, y_part);
  k2_topk<<<TOKENS / 64, 64, 0, stream>>>(y_part, dbias, w, flag_cnt,
                                          flag_list);
  k2b_refine<<<512, 256, 0, stream>>>(x, A, dbias, flag_cnt, flag_list, w);
  k3_out<<<dim3(DDIM / 512, TOKENS / K3_TOK), 256, 0, stream>>>(w, B, out);
}